// Round 3
// baseline (561.824 us; speedup 1.0000x reference)
//
#include <hip/hip_runtime.h>
#include <stdint.h>

#define GAS __attribute__((address_space(1)))
#define LAS __attribute__((address_space(3)))

typedef short bf16x8 __attribute__((ext_vector_type(8)));
typedef float f32x4 __attribute__((ext_vector_type(4)));
typedef unsigned short u16x8 __attribute__((ext_vector_type(8)));

__device__ __forceinline__ unsigned short f2bf(float f) {
  union { float f; uint32_t u; } v; v.f = f;
  uint32_t r = v.u + 0x7FFFu + ((v.u >> 16) & 1u);
  return (unsigned short)(r >> 16);
}

// ------------- transpose + cast: src [R,C] f32 -> dst [C,R] bf16 -------------
__global__ __launch_bounds__(256) void transpose_cvt(const float* __restrict__ src,
                                                     unsigned short* __restrict__ dst,
                                                     int R, int C) {
  __shared__ unsigned short tile[32][33];
  int tx = threadIdx.x, ty = threadIdx.y;  // 32 x 8
  int r0 = blockIdx.y * 32, c0 = blockIdx.x * 32;
#pragma unroll
  for (int i = 0; i < 32; i += 8)
    tile[ty + i][tx] = f2bf(src[(long)(r0 + ty + i) * C + c0 + tx]);
  __syncthreads();
#pragma unroll
  for (int i = 0; i < 32; i += 8)
    dst[(long)(c0 + ty + i) * R + r0 + tx] = tile[tx][ty + i];
}

// -------- bias + relu + bf16 cast epilogue (for split-K accumulated GEMM1) --------
__global__ __launch_bounds__(256) void bias_relu_cvt(const float* __restrict__ acc,
                                                     const float* __restrict__ bias,
                                                     unsigned short* __restrict__ dst) {
  long i = (long)blockIdx.x * 256 + threadIdx.x;  // one u16x8 per thread
  const float4* a4 = (const float4*)acc;
  float4 a = a4[i * 2];
  float4 b = a4[i * 2 + 1];
  int col = (int)((i * 8) & 1023);
  const float4* b4 = (const float4*)(bias + col);
  float4 ba = b4[0], bb = b4[1];
  u16x8 o;
  o[0] = f2bf(fmaxf(a.x + ba.x, 0.f)); o[1] = f2bf(fmaxf(a.y + ba.y, 0.f));
  o[2] = f2bf(fmaxf(a.z + ba.z, 0.f)); o[3] = f2bf(fmaxf(a.w + ba.w, 0.f));
  o[4] = f2bf(fmaxf(b.x + bb.x, 0.f)); o[5] = f2bf(fmaxf(b.y + bb.y, 0.f));
  o[6] = f2bf(fmaxf(b.z + bb.z, 0.f)); o[7] = f2bf(fmaxf(b.w + bb.w, 0.f));
  ((u16x8*)dst)[i] = o;
}

// ---------------- 128x128 bf16 MFMA GEMM, XOR-swizzled LDS, split-K atomic ----------------
// Fixed logical grid 8(x=N) x 32(y=M) x 4(z=K-split), launched flattened 1024 blocks with an
// XCD-aware remap: xcd = b&7 picks the (y,z)-partition; within an XCD, x varies fastest so the
// 8 blocks sharing one A-slice run concurrently on the SAME XCD's L2.
// A_FP32=1: A is fp32 [M,K], converted to bf16 (truncation, v_perm pack) during staging.
// A_FP32=0: A is bf16 [M,K], staged via global_load_lds.
// Bt: [1024,K] bf16 row-major (B transposed). Accumulates via unsafeAtomicAdd into fp32 Cv.
template <int A_FP32>
__global__ __launch_bounds__(256, 2) void gemm_bt(const void* __restrict__ Av,
                                                  const unsigned short* __restrict__ Bt,
                                                  float* __restrict__ Cv, int M, int K,
                                                  int kIters) {
  __shared__ unsigned short lA[128 * 64];  // 16 KB
  __shared__ unsigned short lB[128 * 64];  // 16 KB
  const int tid = threadIdx.x;
  const int lane = tid & 63;
  const int wave = tid >> 6;
  const int wm = wave >> 1, wn = wave & 1;

  // XCD-aware decode of flat block id
  const int b = blockIdx.x;
  const int xcd = b & 7;
  const int slot = b >> 3;
  const int bx = slot & 7;                  // N-block 0..7 (fastest within XCD)
  const int pg = xcd * 16 + (slot >> 3);    // (y,z) pair 0..127
  const int by = pg & 31;
  const int bz = pg >> 5;

  const long rowBase = (long)by * 128;
  const long colBase = (long)bx * 128;
  const int kStart = bz * kIters * 64;

  f32x4 acc[4][4];
#pragma unroll
  for (int i = 0; i < 4; i++)
#pragma unroll
    for (int j = 0; j < 4; j++) acc[i][j] = (f32x4){0.f, 0.f, 0.f, 0.f};

  // Staging: flat f = it*256+tid -> LDS slot (r=f>>3, q=f&7) at byte f*16.
  // XOR swizzle: slot (r,q) holds GLOBAL chunk q^(r&7) -> conflict-free fragment reads.
  long gA[4], gB[4];
#pragma unroll
  for (int it = 0; it < 4; ++it) {
    int f = it * 256 + tid;
    int r = f >> 3;
    int q = f & 7;
    int kq = ((q ^ (r & 7)) * 8) + kStart;
    long ar = rowBase + r;
    if (ar >= M) ar = M - 1;  // clamp: stays in-bounds, C-write masked later
    gA[it] = ar * (long)K + kq;
    gB[it] = ((long)(colBase + r)) * K + kq;
  }

  for (int ki = 0; ki < kIters; ++ki) {
    const long kc = (long)ki * 64;
    if (A_FP32) {
      const uint4* A4 = (const uint4*)Av;
      uint4 t[8];
#pragma unroll
      for (int it = 0; it < 4; ++it) {
        long fi = (gA[it] + kc) >> 2;  // element index /4 (8-float aligned)
        t[2 * it] = A4[fi];
        t[2 * it + 1] = A4[fi + 1];
      }
#pragma unroll
      for (int it = 0; it < 4; ++it) {
        int f = it * 256 + tid;
        uint4 lo = t[2 * it], hi = t[2 * it + 1];
        uint4 o;  // truncate-to-bf16 pack: hi16(f1)<<16 | hi16(f0)
        o.x = __builtin_amdgcn_perm(lo.y, lo.x, 0x07060302u);
        o.y = __builtin_amdgcn_perm(lo.w, lo.z, 0x07060302u);
        o.z = __builtin_amdgcn_perm(hi.y, hi.x, 0x07060302u);
        o.w = __builtin_amdgcn_perm(hi.w, hi.z, 0x07060302u);
        *(uint4*)(lA + f * 8) = o;
      }
    } else {
      const unsigned short* A = (const unsigned short*)Av;
#pragma unroll
      for (int it = 0; it < 4; ++it) {
        int f = it * 256 + tid;
        __builtin_amdgcn_global_load_lds((const GAS void*)(A + gA[it] + kc),
                                         (LAS void*)(lA + f * 8), 16, 0, 0);
      }
    }
#pragma unroll
    for (int it = 0; it < 4; ++it) {
      int f = it * 256 + tid;
      __builtin_amdgcn_global_load_lds((const GAS void*)(Bt + gB[it] + kc),
                                       (LAS void*)(lB + f * 8), 16, 0, 0);
    }
    __syncthreads();
#pragma unroll
    for (int ks = 0; ks < 64; ks += 32) {
      bf16x8 af[4], bf[4];
      const int c = (ks >> 3) + (lane >> 4);   // global chunk needed
      const int slotk = (c ^ (lane & 7)) << 3; // swizzled LDS k-offset (elems)
      const int mr = wm * 64 + (lane & 15);
      const int nr = wn * 64 + (lane & 15);
#pragma unroll
      for (int i = 0; i < 4; i++)
        af[i] = *(const bf16x8*)(lA + (mr + i * 16) * 64 + slotk);
#pragma unroll
      for (int i = 0; i < 4; i++)
        bf[i] = *(const bf16x8*)(lB + (nr + i * 16) * 64 + slotk);
#pragma unroll
      for (int i = 0; i < 4; i++)
#pragma unroll
        for (int j = 0; j < 4; j++)
          acc[i][j] = __builtin_amdgcn_mfma_f32_16x16x32_bf16(af[i], bf[j], acc[i][j], 0, 0, 0);
    }
    __syncthreads();
  }

  // epilogue: C/D layout col=lane&15, row=(lane>>4)*4+reg  [m89-verified]
  const int cq = lane & 15;
  const int rq = (lane >> 4) * 4;
#pragma unroll
  for (int i = 0; i < 4; i++) {
#pragma unroll
    for (int j = 0; j < 4; j++) {
      int col = (int)colBase + wn * 64 + j * 16 + cq;
#pragma unroll
      for (int r = 0; r < 4; r++) {
        long grow = rowBase + wm * 64 + i * 16 + rq + r;
        if (grow < M) unsafeAtomicAdd(&Cv[grow * 1024 + col], acc[i][j][r]);
      }
    }
  }
}

// ---------------- heads: bias+relu on h2 fused in ----------------
__global__ __launch_bounds__(256) void head_kernel(
    const float* __restrict__ H2f, const float* __restrict__ b2,
    const float* __restrict__ wc, const float* __restrict__ bc,
    const float* __restrict__ wr, const float* __restrict__ br,
    const float* __restrict__ boxes,
    float* __restrict__ cls, float* __restrict__ bout, float* __restrict__ rois) {
  const int lane = threadIdx.x & 63;
  const int wave = threadIdx.x >> 6;
  const int row = blockIdx.x * 4 + wave;  // 1000 blocks * 4 waves = 4000 rows
  const float* h = H2f + (long)row * 1024;
  float acc[16];
#pragma unroll
  for (int c = 0; c < 16; c++) acc[c] = 0.f;
#pragma unroll
  for (int i = 0; i < 16; i++) {
    int d = i * 64 + lane;
    float hv = fmaxf(h[d] + b2[d], 0.f);
#pragma unroll
    for (int c = 0; c < 11; c++) acc[c] += hv * wc[d * 11 + c];
#pragma unroll
    for (int c = 0; c < 5; c++) acc[11 + c] += hv * wr[d * 5 + c];
  }
#pragma unroll
  for (int off = 32; off >= 1; off >>= 1) {
#pragma unroll
    for (int c = 0; c < 16; c++) acc[c] += __shfl_down(acc[c], off);
  }
  if (lane == 0) {
#pragma unroll
    for (int c = 0; c < 11; c++) cls[row * 11 + c] = acc[c] + bc[c];
#pragma unroll
    for (int c = 0; c < 5; c++) {
      float rg = acc[11 + c] + br[c];
      float bx = boxes[row * 5 + c];
      bout[row * 5 + c] = bx + rg;
      rois[row * 5 + c] = bx;
    }
  }
}

extern "C" void kernel_launch(void* const* d_in, const int* in_sizes, int n_in,
                              void* d_out, int out_size, void* d_ws, size_t ws_size,
                              hipStream_t stream) {
  const float* features = (const float*)d_in[0];  // [4000,12544] fp32
  const float* boxes = (const float*)d_in[1];     // [4000,5]
  const float* w1 = (const float*)d_in[2];        // [12544,1024]
  const float* b1 = (const float*)d_in[3];
  const float* w2 = (const float*)d_in[4];        // [1024,1024]
  const float* b2 = (const float*)d_in[5];
  const float* wc = (const float*)d_in[6];        // [1024,11]
  const float* bc = (const float*)d_in[7];
  const float* wr = (const float*)d_in[8];        // [1024,5]
  const float* br = (const float*)d_in[9];

  char* ws = (char*)d_ws;
  unsigned short* W1T = (unsigned short*)ws;                    // 25,690,112 B
  unsigned short* W2T = (unsigned short*)(ws + 25690112);       //  2,097,152 B
  unsigned short* H1  = (unsigned short*)(ws + 27787264);       //  8,192,000 B
  float*          H1f = (float*)(ws + 35979264);                // 16,384,000 B
  float*          H2f = (float*)(ws + 52363264);                // 16,384,000 B
  // total ws used: 68,747,264 B

  // 0) zero both split-K accumulators in one memset (H1f and H2f are adjacent)
  hipMemsetAsync(H1f, 0, 32768000, stream);
  // 1) w1 -> W1T bf16 [1024,12544]
  transpose_cvt<<<dim3(32, 392), dim3(32, 8), 0, stream>>>(w1, W1T, 12544, 1024);
  // 2) w2 -> W2T bf16 [1024,1024]
  transpose_cvt<<<dim3(32, 32), dim3(32, 8), 0, stream>>>(w2, W2T, 1024, 1024);
  // 3) GEMM1 split-K x4, fp32 A converted in-staging: H1f += feat @ w1
  gemm_bt<1><<<1024, 256, 0, stream>>>(features, W1T, H1f, 4000, 12544, 49);
  // 4) H1 = bf16(relu(H1f + b1))
  bias_relu_cvt<<<2000, 256, 0, stream>>>(H1f, b1, H1);
  // 5) GEMM2 split-K x4: H2f += H1 @ w2
  gemm_bt<0><<<1024, 256, 0, stream>>>(H1, W2T, H2f, 4000, 1024, 4);
  // 6) heads (b2+relu fused) + box add + rois passthrough
  float* cls = (float*)d_out;   // [4000,11]
  float* bout = cls + 44000;    // [4000,5]
  float* rois = cls + 64000;    // [4000,5]
  head_kernel<<<1000, 256, 0, stream>>>(H2f, b2, wc, bc, wr, br, boxes, cls, bout, rois);
}

// Round 4
// 529.763 us; speedup vs baseline: 1.0605x; 1.0605x over previous
//
#include <hip/hip_runtime.h>
#include <stdint.h>

#define GAS __attribute__((address_space(1)))
#define LAS __attribute__((address_space(3)))

typedef short bf16x8 __attribute__((ext_vector_type(8)));
typedef float f32x4 __attribute__((ext_vector_type(4)));
typedef unsigned short u16x8 __attribute__((ext_vector_type(8)));

__device__ __forceinline__ unsigned short f2bf(float f) {
  union { float f; uint32_t u; } v; v.f = f;
  uint32_t r = v.u + 0x7FFFu + ((v.u >> 16) & 1u);
  return (unsigned short)(r >> 16);
}

// ---------------- fp32 -> bf16 cast, 8 elems/thread ----------------
__global__ __launch_bounds__(256) void cvt_kernel(const float* __restrict__ src,
                                                  unsigned short* __restrict__ dst,
                                                  long n8) {
  long i = (long)blockIdx.x * blockDim.x + threadIdx.x;
  if (i >= n8) return;
  const float4* s4 = (const float4*)src;
  float4 a = s4[i * 2];
  float4 b = s4[i * 2 + 1];
  u16x8 o;
  o[0] = f2bf(a.x); o[1] = f2bf(a.y); o[2] = f2bf(a.z); o[3] = f2bf(a.w);
  o[4] = f2bf(b.x); o[5] = f2bf(b.y); o[6] = f2bf(b.z); o[7] = f2bf(b.w);
  ((u16x8*)dst)[i] = o;
}

// ------------- transpose + cast: src [R,C] f32 -> dst [C,R] bf16 -------------
__global__ __launch_bounds__(256) void transpose_cvt(const float* __restrict__ src,
                                                     unsigned short* __restrict__ dst,
                                                     int R, int C) {
  __shared__ unsigned short tile[32][33];
  int tx = threadIdx.x, ty = threadIdx.y;  // 32 x 8
  int r0 = blockIdx.y * 32, c0 = blockIdx.x * 32;
#pragma unroll
  for (int i = 0; i < 32; i += 8)
    tile[ty + i][tx] = f2bf(src[(long)(r0 + ty + i) * C + c0 + tx]);
  __syncthreads();
#pragma unroll
  for (int i = 0; i < 32; i += 8)
    dst[(long)(c0 + ty + i) * R + r0 + tx] = tile[tx][ty + i];
}

// -------- bias + relu + bf16 cast epilogue (for split-K accumulated GEMM1) --------
__global__ __launch_bounds__(256) void bias_relu_cvt(const float* __restrict__ acc,
                                                     const float* __restrict__ bias,
                                                     unsigned short* __restrict__ dst) {
  long i = (long)blockIdx.x * 256 + threadIdx.x;  // one u16x8 per thread
  const float4* a4 = (const float4*)acc;
  float4 a = a4[i * 2];
  float4 b = a4[i * 2 + 1];
  int col = (int)((i * 8) & 1023);
  const float4* b4 = (const float4*)(bias + col);
  float4 ba = b4[0], bb = b4[1];
  u16x8 o;
  o[0] = f2bf(fmaxf(a.x + ba.x, 0.f)); o[1] = f2bf(fmaxf(a.y + ba.y, 0.f));
  o[2] = f2bf(fmaxf(a.z + ba.z, 0.f)); o[3] = f2bf(fmaxf(a.w + ba.w, 0.f));
  o[4] = f2bf(fmaxf(b.x + bb.x, 0.f)); o[5] = f2bf(fmaxf(b.y + bb.y, 0.f));
  o[6] = f2bf(fmaxf(b.z + bb.z, 0.f)); o[7] = f2bf(fmaxf(b.w + bb.w, 0.f));
  ((u16x8*)dst)[i] = o;
}

// ---------- GEMM1: 128x128 bf16, XOR-swizzled LDS, split-K x4, atomic ----------
// A: [M,K] bf16, Bt: [1024,K] bf16 (B transposed). Logical grid 8(xN) x 32(yM) x 4(zK)
// flattened to 1024 with XCD remap: the 8 N-blocks sharing one A-slice land on ONE XCD.
__global__ __launch_bounds__(256, 2) void gemm1_atomic(const unsigned short* __restrict__ A,
                                                       const unsigned short* __restrict__ Bt,
                                                       float* __restrict__ Cv, int M, int K,
                                                       int kIters) {
  __shared__ unsigned short lA[128 * 64];  // 16 KB
  __shared__ unsigned short lB[128 * 64];  // 16 KB
  const int tid = threadIdx.x;
  const int lane = tid & 63;
  const int wave = tid >> 6;
  const int wm = wave >> 1, wn = wave & 1;

  const int b = blockIdx.x;
  const int xcd = b & 7;
  const int slot = b >> 3;
  const int bx = slot & 7;                // N-block, fastest within XCD
  const int pg = xcd * 16 + (slot >> 3);  // (y,z) 0..127
  const int by = pg & 31;
  const int bz = pg >> 5;

  const long rowBase = (long)by * 128;
  const long colBase = (long)bx * 128;
  const int kStart = bz * kIters * 64;

  f32x4 acc[4][4];
#pragma unroll
  for (int i = 0; i < 4; i++)
#pragma unroll
    for (int j = 0; j < 4; j++) acc[i][j] = (f32x4){0.f, 0.f, 0.f, 0.f};

  // flat f = it*256+tid -> LDS slot (r=f>>3, q=f&7) at byte f*16 (wave-uniform+lane*16).
  // XOR swizzle: slot (r,q) holds GLOBAL chunk q^(r&7) -> conflict-free fragment reads.
  long gA[4], gB[4];
#pragma unroll
  for (int it = 0; it < 4; ++it) {
    int f = it * 256 + tid;
    int r = f >> 3;
    int q = f & 7;
    int kq = ((q ^ (r & 7)) * 8) + kStart;
    long ar = rowBase + r;
    if (ar >= M) ar = M - 1;  // clamp: stays in-bounds, C-write masked later
    gA[it] = ar * (long)K + kq;
    gB[it] = ((long)(colBase + r)) * K + kq;
  }

  for (int ki = 0; ki < kIters; ++ki) {
    const long kc = (long)ki * 64;
#pragma unroll
    for (int it = 0; it < 4; ++it) {
      int f = it * 256 + tid;
      __builtin_amdgcn_global_load_lds((const GAS void*)(A + gA[it] + kc),
                                       (LAS void*)(lA + f * 8), 16, 0, 0);
    }
#pragma unroll
    for (int it = 0; it < 4; ++it) {
      int f = it * 256 + tid;
      __builtin_amdgcn_global_load_lds((const GAS void*)(Bt + gB[it] + kc),
                                       (LAS void*)(lB + f * 8), 16, 0, 0);
    }
    __syncthreads();
#pragma unroll
    for (int ks = 0; ks < 64; ks += 32) {
      bf16x8 af[4], bf[4];
      const int c = (ks >> 3) + (lane >> 4);
      const int slotk = (c ^ (lane & 7)) << 3;
      const int mr = wm * 64 + (lane & 15);
      const int nr = wn * 64 + (lane & 15);
#pragma unroll
      for (int i = 0; i < 4; i++)
        af[i] = *(const bf16x8*)(lA + (mr + i * 16) * 64 + slotk);
#pragma unroll
      for (int i = 0; i < 4; i++)
        bf[i] = *(const bf16x8*)(lB + (nr + i * 16) * 64 + slotk);
#pragma unroll
      for (int i = 0; i < 4; i++)
#pragma unroll
        for (int j = 0; j < 4; j++)
          acc[i][j] = __builtin_amdgcn_mfma_f32_16x16x32_bf16(af[i], bf[j], acc[i][j], 0, 0, 0);
    }
    __syncthreads();
  }

  // C/D layout: col=lane&15, row=(lane>>4)*4+reg  [m89-verified]
  const int cq = lane & 15;
  const int rq = (lane >> 4) * 4;
#pragma unroll
  for (int i = 0; i < 4; i++) {
#pragma unroll
    for (int j = 0; j < 4; j++) {
      int col = (int)colBase + wn * 64 + j * 16 + cq;
#pragma unroll
      for (int r = 0; r < 4; r++) {
        long grow = rowBase + wm * 64 + i * 16 + rq + r;
        if (grow < M) unsafeAtomicAdd(&Cv[grow * 1024 + col], acc[i][j][r]);
      }
    }
  }
}

// ---------- GEMM2: 128x64 tile, no split-K, direct store, bias+relu ----------
// A: [M,1024] bf16 (H1), Bt: [1024,1024] bf16 (w2 transposed). Grid 512 = 16(xN) x 32(yM),
// XCD remap: 16 N-blocks of one A-slice per XCD pair-group.
__global__ __launch_bounds__(256, 2) void gemm2_direct(const unsigned short* __restrict__ A,
                                                       const unsigned short* __restrict__ Bt,
                                                       const float* __restrict__ bias,
                                                       float* __restrict__ Cv, int M) {
  const int K = 1024;
  __shared__ unsigned short lA[128 * 64];  // 16 KB
  __shared__ unsigned short lB[64 * 64];   // 8 KB
  const int tid = threadIdx.x;
  const int lane = tid & 63;
  const int wave = tid >> 6;
  const int wm = wave >> 1, wn = wave & 1;  // wave tile 64m x 32n

  const int b = blockIdx.x;
  const int xcd = b & 7;
  const int slot = b >> 3;               // 0..63
  const int bx = slot & 15;              // N-block 0..15, fastest within XCD
  const int by = xcd * 4 + (slot >> 4);  // M-block 0..31

  const long rowBase = (long)by * 128;
  const long colBase = (long)bx * 64;

  f32x4 acc[4][2];
#pragma unroll
  for (int i = 0; i < 4; i++)
#pragma unroll
    for (int j = 0; j < 2; j++) acc[i][j] = (f32x4){0.f, 0.f, 0.f, 0.f};

  long gA[4], gB[2];
#pragma unroll
  for (int it = 0; it < 4; ++it) {
    int f = it * 256 + tid;
    int r = f >> 3;
    int q = f & 7;
    int kq = (q ^ (r & 7)) * 8;
    long ar = rowBase + r;
    if (ar >= M) ar = M - 1;
    gA[it] = ar * (long)K + kq;
  }
#pragma unroll
  for (int it = 0; it < 2; ++it) {
    int f = it * 256 + tid;
    int r = f >> 3;
    int q = f & 7;
    int kq = (q ^ (r & 7)) * 8;
    gB[it] = ((long)(colBase + r)) * K + kq;
  }

  for (int ki = 0; ki < 16; ++ki) {
    const long kc = (long)ki * 64;
#pragma unroll
    for (int it = 0; it < 4; ++it) {
      int f = it * 256 + tid;
      __builtin_amdgcn_global_load_lds((const GAS void*)(A + gA[it] + kc),
                                       (LAS void*)(lA + f * 8), 16, 0, 0);
    }
#pragma unroll
    for (int it = 0; it < 2; ++it) {
      int f = it * 256 + tid;
      __builtin_amdgcn_global_load_lds((const GAS void*)(Bt + gB[it] + kc),
                                       (LAS void*)(lB + f * 8), 16, 0, 0);
    }
    __syncthreads();
#pragma unroll
    for (int ks = 0; ks < 64; ks += 32) {
      bf16x8 af[4], bf[2];
      const int c = (ks >> 3) + (lane >> 4);
      const int slotk = (c ^ (lane & 7)) << 3;
      const int mr = wm * 64 + (lane & 15);
      const int nr = wn * 32 + (lane & 15);
#pragma unroll
      for (int i = 0; i < 4; i++)
        af[i] = *(const bf16x8*)(lA + (mr + i * 16) * 64 + slotk);
#pragma unroll
      for (int j = 0; j < 2; j++)
        bf[j] = *(const bf16x8*)(lB + (nr + j * 16) * 64 + slotk);
#pragma unroll
      for (int i = 0; i < 4; i++)
#pragma unroll
        for (int j = 0; j < 2; j++)
          acc[i][j] = __builtin_amdgcn_mfma_f32_16x16x32_bf16(af[i], bf[j], acc[i][j], 0, 0, 0);
    }
    __syncthreads();
  }

  const int cq = lane & 15;
  const int rq = (lane >> 4) * 4;
#pragma unroll
  for (int i = 0; i < 4; i++) {
#pragma unroll
    for (int j = 0; j < 2; j++) {
      int col = (int)colBase + wn * 32 + j * 16 + cq;
      float bv = bias[col];
#pragma unroll
      for (int r = 0; r < 4; r++) {
        long grow = rowBase + wm * 64 + i * 16 + rq + r;
        if (grow < M) {
          float v = acc[i][j][r] + bv;
          Cv[grow * 1024 + col] = v > 0.f ? v : 0.f;
        }
      }
    }
  }
}

// ---------------- heads ----------------
__global__ __launch_bounds__(256) void head_kernel(
    const float* __restrict__ H2, const float* __restrict__ wc, const float* __restrict__ bc,
    const float* __restrict__ wr, const float* __restrict__ br, const float* __restrict__ boxes,
    float* __restrict__ cls, float* __restrict__ bout, float* __restrict__ rois) {
  const int lane = threadIdx.x & 63;
  const int wave = threadIdx.x >> 6;
  const int row = blockIdx.x * 4 + wave;  // 1000 * 4 = 4000 rows
  const float* h = H2 + (long)row * 1024;
  float acc[16];
#pragma unroll
  for (int c = 0; c < 16; c++) acc[c] = 0.f;
#pragma unroll
  for (int i = 0; i < 16; i++) {
    int d = i * 64 + lane;
    float hv = h[d];
#pragma unroll
    for (int c = 0; c < 11; c++) acc[c] += hv * wc[d * 11 + c];
#pragma unroll
    for (int c = 0; c < 5; c++) acc[11 + c] += hv * wr[d * 5 + c];
  }
#pragma unroll
  for (int off = 32; off >= 1; off >>= 1) {
#pragma unroll
    for (int c = 0; c < 16; c++) acc[c] += __shfl_down(acc[c], off);
  }
  if (lane == 0) {
#pragma unroll
    for (int c = 0; c < 11; c++) cls[row * 11 + c] = acc[c] + bc[c];
#pragma unroll
    for (int c = 0; c < 5; c++) {
      float rg = acc[11 + c] + br[c];
      float bx = boxes[row * 5 + c];
      bout[row * 5 + c] = bx + rg;
      rois[row * 5 + c] = bx;
    }
  }
}

extern "C" void kernel_launch(void* const* d_in, const int* in_sizes, int n_in,
                              void* d_out, int out_size, void* d_ws, size_t ws_size,
                              hipStream_t stream) {
  const float* features = (const float*)d_in[0];  // [4000,12544] fp32
  const float* boxes = (const float*)d_in[1];
  const float* w1 = (const float*)d_in[2];  // [12544,1024]
  const float* b1 = (const float*)d_in[3];
  const float* w2 = (const float*)d_in[4];  // [1024,1024]
  const float* b2 = (const float*)d_in[5];
  const float* wc = (const float*)d_in[6];  // [1024,11]
  const float* bc = (const float*)d_in[7];
  const float* wr = (const float*)d_in[8];  // [1024,5]
  const float* br = (const float*)d_in[9];

  char* ws = (char*)d_ws;
  unsigned short* Xb  = (unsigned short*)ws;                // 100,352,000 B
  unsigned short* W1T = (unsigned short*)(ws + 100352000);  //  25,690,112 B
  unsigned short* W2T = (unsigned short*)(ws + 126042112);  //   2,097,152 B
  unsigned short* H1  = (unsigned short*)(ws + 128139264);  //   8,192,000 B
  float*          H1f = (float*)(ws + 136331264);           //  16,384,000 B
  float*          H2  = (float*)(ws + 152715264);           //  16,384,000 B
  // total ws used: 169,099,264 B

  // 0) zero split-K accumulator
  hipMemsetAsync(H1f, 0, 16384000, stream);
  // 1) features -> bf16
  cvt_kernel<<<24500, 256, 0, stream>>>(features, Xb, 6272000);
  // 2) w1 -> W1T bf16 [1024,12544]
  transpose_cvt<<<dim3(32, 392), dim3(32, 8), 0, stream>>>(w1, W1T, 12544, 1024);
  // 3) w2 -> W2T bf16 [1024,1024]
  transpose_cvt<<<dim3(32, 32), dim3(32, 8), 0, stream>>>(w2, W2T, 1024, 1024);
  // 4) GEMM1 split-K x4 atomic: H1f += Xb @ w1
  gemm1_atomic<<<1024, 256, 0, stream>>>(Xb, W1T, H1f, 4000, 12544, 49);
  // 5) H1 = bf16(relu(H1f + b1))
  bias_relu_cvt<<<2000, 256, 0, stream>>>(H1f, b1, H1);
  // 6) GEMM2 direct: H2 = relu(H1 @ w2 + b2)
  gemm2_direct<<<512, 256, 0, stream>>>(H1, W2T, b2, H2, 4000);
  // 7) heads
  float* cls = (float*)d_out;   // [4000,11]
  float* bout = cls + 44000;    // [4000,5]
  float* rois = cls + 64000;    // [4000,5]
  head_kernel<<<1000, 256, 0, stream>>>(H2, wc, bc, wr, br, boxes, cls, bout, rois);
}